// Round 1
// baseline (527.442 us; speedup 1.0000x reference)
//
#include <hip/hip_runtime.h>
#include <stdint.h>

#define BATCH 32
#define NANCH 25200
#define CH 85
#define NCLS 80
#define TOPK 512
#define CONF_THRE 0.7f
#define NMS_THRE 0.45f
#define CLS_OFF 4096.0f

typedef unsigned long long u64;
typedef unsigned int u32;

// ws layout (bytes):
//   [0, 3225600)          u32 conf32[32][25200]   (conf bits, 0 if below threshold)
//   [3225600, +32768)     u32 hist[32][256]       per-image histogram (global atomics)
#define OFF_CONF 0
#define OFF_HIST 3225600

// ---- k0: zero the histogram (workspace is poisoned, not zeroed) ----
__global__ __launch_bounds__(256) void zero_kernel(u32* __restrict__ histG) {
    histG[blockIdx.x * 256 + threadIdx.x] = 0u;
}

// ---- k1 scan: wave-transposed, no LDS, no barriers. 16 lanes per anchor.
//      Fused per-image histogram of top-8 mantissa bits (global atomics). ----
__global__ __launch_bounds__(256) void scan_kernel(const float* __restrict__ pred,
                                                   u32* __restrict__ conf32,
                                                   u32* __restrict__ histG) {
    const int tid = threadIdx.x;
    const int lane = tid & 63;
    const int wv = tid >> 6;
    const int g = lane >> 4;          // anchor-in-wave 0..3
    const int l = lane & 15;          // lane-in-group
    const int a = blockIdx.x * 16 + wv * 4 + g;     // flat img*NANCH+anchor
    const size_t base = (size_t)a * CH;

    float m = -1.0f, obj = 0.0f;
    {   // p = l*4 .. l*4+3  (covers 0..63)
        const float4 q = *(const float4*)(pred + base + (l << 2));
        const int p = l << 2;
        if (p + 0 >= 5) m = fmaxf(m, q.x); else if (p + 0 == 4) obj = q.x;
        if (p + 1 >= 5) m = fmaxf(m, q.y); else if (p + 1 == 4) obj = q.y;
        if (p + 2 >= 5) m = fmaxf(m, q.z); else if (p + 2 == 4) obj = q.z;
        if (p + 3 >= 5) m = fmaxf(m, q.w); else if (p + 3 == 4) obj = q.w;
    }
    if (l < 5) {                      // p = 64 .. 83 (all classes)
        const float4 q = *(const float4*)(pred + base + 64 + (l << 2));
        m = fmaxf(fmaxf(m, fmaxf(q.x, q.y)), fmaxf(q.z, q.w));
    } else if (l == 5) {              // p = 84
        m = fmaxf(m, pred[base + 84]);
    }
    #pragma unroll
    for (int off = 1; off < 16; off <<= 1) m = fmaxf(m, __shfl_xor(m, off));
    const float ob = __shfl(obj, (lane & 48) + 1);  // lane g*16+1 holds p==4
    const float conf = ob * m;
    if (l == 0) {
        const bool ok = conf >= CONF_THRE;
        const u32 c = __float_as_uint(conf);
        conf32[a] = ok ? c : 0u;
        if (ok) {
            const int img = a / NANCH;
            atomicAdd(&histG[img * 256 + ((c >> 15) & 255u)], 1u);   // bins 102..255
        }
    }
}

// ---- k2 mega: per-image select + rank-sort + gather + IoU + greedy NMS + output.
//      All intermediate state lives in LDS (~72 KB); one block per image. ----
__global__ __launch_bounds__(1024) void mega_kernel(const float* __restrict__ pred,
                                                    const u32* __restrict__ conf32,
                                                    const u32* __restrict__ histG,
                                                    float* __restrict__ out) {
    __shared__ u64 sbuf[1024];              //  8 KB
    __shared__ u64 sorted[1024];            //  8 KB
    __shared__ u64 smask[TOPK * 8];         // 32 KB  iou suppress bitmask
    __shared__ float sdet[TOPK * 6];        // 12 KB
    __shared__ float bx1[TOPK], by1[TOPK], bx2[TOPK], by2[TOPK], bar[TOPK];  // 10 KB
    __shared__ unsigned char val[TOPK];     // 0.5 KB
    __shared__ u32 wtot[4];
    __shared__ u32 s_cnt, s_pivot;
    __shared__ u64 kwinit[8];
    __shared__ u64 kw8[8];

    const int img = blockIdx.x;
    const int tid = threadIdx.x;
    const int lane = tid & 63;
    const int wv = tid >> 6;

    if (tid == 0) { s_cnt = 0u; s_pivot = 0u; }  // pivot 0 => T=0x3F000000 selects all valid

    // threshold pivot from per-image histogram: inclusive suffix scan over 256 bins
    u32 v = 0, s = 0;
    if (tid < 256) {
        v = histG[(size_t)img * 256 + tid];
        s = v;
        #pragma unroll
        for (int off = 1; off < 64; off <<= 1) {
            const u32 t = __shfl_down(s, off);
            if (lane + off < 64) s += t;
        }
        if (lane == 0) wtot[wv] = s;
    }
    __syncthreads();
    if (tid < 256) {
        u32 add = 0;
        for (int w2 = wv + 1; w2 < 4; ++w2) add += wtot[w2];
        const u32 sfull = s + add;        // count in bins >= tid
        const u32 snext = sfull - v;      // count in bins >  tid
        if (sfull >= TOPK && snext < TOPK) s_pivot = (u32)tid;
    }
    __syncthreads();
    const u32 T = 0x3F000000u | (s_pivot << 15);

    // single-pass compact conf >= T (order-free; rank sort restores exact order)
    const u32* cd = conf32 + (size_t)img * NANCH;
    for (int i = tid; i < NANCH; i += 1024) {
        const u32 c = cd[i];
        if (c >= T) {
            const u32 pos = atomicAdd(&s_cnt, 1u);
            if (pos < 1024u)
                sbuf[pos] = ((u64)c << 32) | (u64)(0xFFFFFFFFu - (u32)i);
        }
    }
    __syncthreads();
    const u32 mc = (s_cnt > 1024u) ? 1024u : s_cnt;

    // rank sort (keys unique by anchor): rank = #{key' > key}
    sorted[tid] = 0ull;
    u32 rank = 0; u64 my = 0ull;
    if (tid < (int)mc) {
        my = sbuf[tid];
        for (u32 i = 0; i < mc; ++i) rank += (sbuf[i] > my) ? 1u : 0u;
    }
    __syncthreads();
    if (tid < (int)mc && rank < 1024u) sorted[rank] = my;
    __syncthreads();

    // gather: one wave per row pair (r, r+256) for 2-deep load pipelining
    for (int r0 = wv; r0 < 256; r0 += 16) {
        const int rA = r0, rB = r0 + 256;
        const u64 keyA = sorted[rA];
        const u64 keyB = sorted[rB];
        const float confA = __uint_as_float((u32)(keyA >> 32));
        const float confB = __uint_as_float((u32)(keyB >> 32));
        const bool okA = confA >= CONF_THRE;
        const bool okB = confB >= CONF_THRE;
        float vA = -1.0f, vB = -1.0f;
        float cxA = 0.f, cyA = 0.f, wwA = 0.f, hhA = 0.f;
        float cxB = 0.f, cyB = 0.f, wwB = 0.f, hhB = 0.f;
        int ciA = lane, ciB = lane;
        if (okA) {
            const u32 anchor = 0xFFFFFFFFu - (u32)(keyA & 0xFFFFFFFFull);
            const float* row = pred + ((size_t)img * NANCH + anchor) * CH;
            vA = row[5 + lane];
            if (lane < 16) {
                const float v2 = row[69 + lane];
                if (v2 > vA) { vA = v2; ciA = 64 + lane; }
            }
            if (lane == 0) { cxA = row[0]; cyA = row[1]; wwA = row[2]; hhA = row[3]; }
        }
        if (okB) {
            const u32 anchor = 0xFFFFFFFFu - (u32)(keyB & 0xFFFFFFFFull);
            const float* row = pred + ((size_t)img * NANCH + anchor) * CH;
            vB = row[5 + lane];
            if (lane < 16) {
                const float v2 = row[69 + lane];
                if (v2 > vB) { vB = v2; ciB = 64 + lane; }
            }
            if (lane == 0) { cxB = row[0]; cyB = row[1]; wwB = row[2]; hhB = row[3]; }
        }
        // argmax reduce, first-max tie rule (lowest class index wins)
        #pragma unroll
        for (int off = 32; off > 0; off >>= 1) {
            const float ov = __shfl_xor(vA, off);
            const int oi = __shfl_xor(ciA, off);
            if (ov > vA || (ov == vA && oi < ciA)) { vA = ov; ciA = oi; }
        }
        #pragma unroll
        for (int off = 32; off > 0; off >>= 1) {
            const float ov = __shfl_xor(vB, off);
            const int oi = __shfl_xor(ciB, off);
            if (ov > vB || (ov == vB && oi < ciB)) { vB = ov; ciB = oi; }
        }
        if (lane == 0) {
            {
                const float clsf = okA ? (float)ciA : 0.0f;
                const float hw = wwA * 0.5f, hh = hhA * 0.5f;
                const float x1 = cxA - hw, y1 = cyA - hh, x2 = cxA + hw, y2 = cyA + hh;
                const float off = clsf * CLS_OFF;
                const float X1 = x1 + off, Y1 = y1 + off, X2 = x2 + off, Y2 = y2 + off;
                bx1[rA] = X1; by1[rA] = Y1; bx2[rA] = X2; by2[rA] = Y2;
                bar[rA] = (X2 - X1) * (Y2 - Y1);
                sdet[rA * 6 + 0] = x1; sdet[rA * 6 + 1] = y1;
                sdet[rA * 6 + 2] = x2; sdet[rA * 6 + 3] = y2;
                sdet[rA * 6 + 4] = okA ? confA : 0.0f;
                sdet[rA * 6 + 5] = clsf;
                val[rA] = okA ? 1 : 0;
            }
            {
                const float clsf = okB ? (float)ciB : 0.0f;
                const float hw = wwB * 0.5f, hh = hhB * 0.5f;
                const float x1 = cxB - hw, y1 = cyB - hh, x2 = cxB + hw, y2 = cyB + hh;
                const float off = clsf * CLS_OFF;
                const float X1 = x1 + off, Y1 = y1 + off, X2 = x2 + off, Y2 = y2 + off;
                bx1[rB] = X1; by1[rB] = Y1; bx2[rB] = X2; by2[rB] = Y2;
                bar[rB] = (X2 - X1) * (Y2 - Y1);
                sdet[rB * 6 + 0] = x1; sdet[rB * 6 + 1] = y1;
                sdet[rB * 6 + 2] = x2; sdet[rB * 6 + 3] = y2;
                sdet[rB * 6 + 4] = okB ? confB : 0.0f;
                sdet[rB * 6 + 5] = clsf;
                val[rB] = okB ? 1 : 0;
            }
        }
    }
    __syncthreads();

    // valid bitmask (waves 0..7 cover tid < 512)
    if (tid < TOPK) {
        const u64 vb = __ballot(val[tid] != 0);
        if (lane == 0) kwinit[wv] = vb;
    }

    // IoU: register-tiled. Each lane caches its 8 j-boxes (j = jb*64+lane);
    // each wave owns i in [wv*32, wv*32+32) read as LDS broadcast.
    float jx1[8], jy1[8], jx2[8], jy2[8], jar[8];
    #pragma unroll
    for (int jb = 0; jb < 8; ++jb) {
        const int j = jb * 64 + lane;
        jx1[jb] = bx1[j]; jy1[jb] = by1[j];
        jx2[jb] = bx2[j]; jy2[jb] = by2[j];
        jar[jb] = bar[j];
    }
    for (int i = wv * 32; i < wv * 32 + 32; ++i) {
        const float ix1 = bx1[i], iy1 = by1[i], ix2 = bx2[i], iy2 = by2[i], iar = bar[i];
        #pragma unroll
        for (int jb = 0; jb < 8; ++jb) {
            const int j = jb * 64 + lane;
            bool sup = false;
            if (j > i) {
                const float xx1 = fmaxf(ix1, jx1[jb]);
                const float yy1 = fmaxf(iy1, jy1[jb]);
                const float xx2 = fminf(ix2, jx2[jb]);
                const float yy2 = fminf(iy2, jy2[jb]);
                const float iw = fmaxf(xx2 - xx1, 0.0f);
                const float ih = fmaxf(yy2 - yy1, 0.0f);
                const float inter = iw * ih;
                const float uni = iar + jar[jb] - inter;
                const float iou = inter / uni;  // IEEE div, NaN>thre == false (matches ref)
                sup = iou > NMS_THRE;
            }
            const u64 bm = __ballot(sup);
            if (lane == 0) smask[i * 8 + jb] = bm;
        }
    }
    __syncthreads();

    // greedy: sequential NMS, single wave, 4-deep LDS prefetch, branchless update
    if (wv == 0) {
        const bool ld = lane < 8;
        u64 kw = ld ? kwinit[lane] : 0ull;
        u64 p0 = ld ? smask[0 * 8 + lane] : 0ull;
        u64 p1 = ld ? smask[1 * 8 + lane] : 0ull;
        u64 p2 = ld ? smask[2 * 8 + lane] : 0ull;
        u64 p3 = ld ? smask[3 * 8 + lane] : 0ull;
        for (int i = 0; i < TOPK; i += 4) {
            {
                const u64 w = __shfl(kw, i >> 6);
                const u64 bit = (w >> (i & 63)) & 1ull;
                kw &= ~(p0 & (0ull - bit));
                p0 = (ld && i + 4 < TOPK) ? smask[(i + 4) * 8 + lane] : 0ull;
            }
            {
                const u64 w = __shfl(kw, (i + 1) >> 6);
                const u64 bit = (w >> ((i + 1) & 63)) & 1ull;
                kw &= ~(p1 & (0ull - bit));
                p1 = (ld && i + 5 < TOPK) ? smask[(i + 5) * 8 + lane] : 0ull;
            }
            {
                const u64 w = __shfl(kw, (i + 2) >> 6);
                const u64 bit = (w >> ((i + 2) & 63)) & 1ull;
                kw &= ~(p2 & (0ull - bit));
                p2 = (ld && i + 6 < TOPK) ? smask[(i + 6) * 8 + lane] : 0ull;
            }
            {
                const u64 w = __shfl(kw, (i + 3) >> 6);
                const u64 bit = (w >> ((i + 3) & 63)) & 1ull;
                kw &= ~(p3 & (0ull - bit));
                p3 = (ld && i + 7 < TOPK) ? smask[(i + 7) * 8 + lane] : 0ull;
            }
        }
        if (ld) kw8[lane] = kw;
    }
    __syncthreads();

    // outputs
    float* det_out = out + (size_t)img * (TOPK * 6);
    float* keep_out = out + (size_t)BATCH * TOPK * 6 + (size_t)img * TOPK;
    for (int idx = tid; idx < TOPK * 6; idx += 1024) {
        const int r = idx / 6;
        const float kf = ((kw8[r >> 6] >> (r & 63)) & 1ull) ? 1.0f : 0.0f;
        det_out[idx] = sdet[idx] * kf;
    }
    if (tid < TOPK) {
        keep_out[tid] = ((kw8[tid >> 6] >> (tid & 63)) & 1ull) ? 1.0f : 0.0f;
    }
}

extern "C" void kernel_launch(void* const* d_in, const int* in_sizes, int n_in,
                              void* d_out, int out_size, void* d_ws, size_t ws_size,
                              hipStream_t stream) {
    const float* pred = (const float*)d_in[0];
    float* out = (float*)d_out;
    char* ws = (char*)d_ws;
    u32* conf32 = (u32*)(ws + OFF_CONF);
    u32* histG = (u32*)(ws + OFF_HIST);

    zero_kernel<<<BATCH, 256, 0, stream>>>(histG);
    scan_kernel<<<(BATCH * NANCH) / 16, 256, 0, stream>>>(pred, conf32, histG);
    mega_kernel<<<BATCH, 1024, 0, stream>>>(pred, conf32, histG, out);
}

// Round 2
// 485.704 us; speedup vs baseline: 1.0859x; 1.0859x over previous
//
#include <hip/hip_runtime.h>
#include <stdint.h>

#define BATCH 32
#define NANCH 25200
#define CH 85
#define NCLS 80
#define TOPK 512
#define CONF_THRE 0.7f
#define NMS_THRE 0.45f
#define CLS_OFF 4096.0f

typedef unsigned long long u64;
typedef unsigned int u32;

// ws layout (bytes):
//   [0, 3225600)          u32 conf32[32][25200]    (conf bits, 0 if below threshold)
//   [3225600, +327680)    float nms[32][5][512]    x1,y1,x2,y2,area (class-offset)
//   [3553280, +393216)    float det[32][512][6]
//   [3946496, +2048)      u64 valid[32][8]
//   [3948544, +1048576)   u64 mask[32][512][8]
#define OFF_CONF  0
#define OFF_NMS   3225600
#define OFF_DET   3553280
#define OFF_VALID 3946496
#define OFF_MASK  3948544

// ---- k1 scan: wave-transposed, no LDS, no barriers. 16 lanes per anchor. ----
__global__ __launch_bounds__(256) void scan_kernel(const float* __restrict__ pred,
                                                   u32* __restrict__ conf32) {
    const int tid = threadIdx.x;
    const int lane = tid & 63;
    const int wv = tid >> 6;
    const int g = lane >> 4;          // anchor-in-wave 0..3
    const int l = lane & 15;          // lane-in-group
    const int a = blockIdx.x * 16 + wv * 4 + g;     // flat img*NANCH+anchor
    const size_t base = (size_t)a * CH;

    float m = -1.0f, obj = 0.0f;
    {   // p = l*4 .. l*4+3  (covers 0..63)
        const float4 q = *(const float4*)(pred + base + (l << 2));
        const int p = l << 2;
        if (p + 0 >= 5) m = fmaxf(m, q.x); else if (p + 0 == 4) obj = q.x;
        if (p + 1 >= 5) m = fmaxf(m, q.y); else if (p + 1 == 4) obj = q.y;
        if (p + 2 >= 5) m = fmaxf(m, q.z); else if (p + 2 == 4) obj = q.z;
        if (p + 3 >= 5) m = fmaxf(m, q.w); else if (p + 3 == 4) obj = q.w;
    }
    if (l < 5) {                      // p = 64 .. 83 (all classes)
        const float4 q = *(const float4*)(pred + base + 64 + (l << 2));
        m = fmaxf(fmaxf(m, fmaxf(q.x, q.y)), fmaxf(q.z, q.w));
    } else if (l == 5) {              // p = 84
        m = fmaxf(m, pred[base + 84]);
    }
    #pragma unroll
    for (int off = 1; off < 16; off <<= 1) m = fmaxf(m, __shfl_xor(m, off));
    const float ob = __shfl(obj, (lane & 48) + 1);  // lane g*16+1 holds p==4
    const float conf = ob * m;
    if (l == 0)
        conf32[a] = (conf >= CONF_THRE) ? __float_as_uint(conf) : 0u;
}

// ---- k2: fused hist + threshold + single-pass compact + rank sort + gather ----
//      (hist built in LDS on the first conf32 pass; compaction pass is L2-hot)
__global__ __launch_bounds__(1024) void select_kernel(const float* __restrict__ pred,
                                                      const u32* __restrict__ conf32,
                                                      float* __restrict__ nmsG,
                                                      float* __restrict__ detG,
                                                      u64* __restrict__ validG) {
    __shared__ u64 sbuf[1024];
    __shared__ u64 sorted[1024];
    __shared__ u32 hist[256];
    __shared__ u32 wtot[4];
    __shared__ u32 s_cnt, s_pivot;
    __shared__ unsigned char val[TOPK];

    const int img = blockIdx.x;
    const int tid = threadIdx.x;
    const int lane = tid & 63;
    const int wv = tid >> 6;

    if (tid == 0) { s_cnt = 0u; s_pivot = 0u; }   // pivot 0 => T=0x3F000000 selects all valid
    if (tid < 256) hist[tid] = 0u;
    __syncthreads();

    // pass 1: build 256-bin histogram of top-8 mantissa bits (valid bins 102..255)
    const u32* cd = conf32 + (size_t)img * NANCH;
    for (int i = tid; i < NANCH; i += 1024) {
        const u32 c = cd[i];
        if (c) atomicAdd(&hist[(c >> 15) & 255u], 1u);
    }
    __syncthreads();

    // inclusive suffix scan over 256 bins (4 waves + cross-wave totals)
    u32 v = 0, s = 0;
    if (tid < 256) {
        v = hist[tid]; s = v;
        #pragma unroll
        for (int off = 1; off < 64; off <<= 1) {
            const u32 t = __shfl_down(s, off);
            if (lane + off < 64) s += t;
        }
        if (lane == 0) wtot[wv] = s;
    }
    __syncthreads();
    if (tid < 256) {
        u32 add = 0;
        for (int w2 = wv + 1; w2 < 4; ++w2) add += wtot[w2];
        const u32 sfull = s + add;        // count in bins >= tid
        const u32 snext = sfull - v;      // count in bins >  tid
        if (sfull >= TOPK && snext < TOPK) s_pivot = (u32)tid;
    }
    __syncthreads();
    const u32 T = 0x3F000000u | (s_pivot << 15);

    // pass 2 (L2-hot): compact conf >= T (order-free; rank sort restores exact order)
    for (int i = tid; i < NANCH; i += 1024) {
        const u32 c = cd[i];
        if (c >= T) {
            const u32 pos = atomicAdd(&s_cnt, 1u);
            if (pos < 1024u)
                sbuf[pos] = ((u64)c << 32) | (u64)(0xFFFFFFFFu - (u32)i);
        }
    }
    __syncthreads();
    const u32 mc = (s_cnt > 1024u) ? 1024u : s_cnt;

    // rank sort (keys unique by anchor): rank = #{key' > key}
    sorted[tid] = 0ull;
    u32 rank = 0; u64 my = 0ull;
    if (tid < (int)mc) {
        my = sbuf[tid];
        for (u32 i = 0; i < mc; ++i) rank += (sbuf[i] > my) ? 1u : 0u;
    }
    __syncthreads();
    if (tid < (int)mc && rank < 1024u) sorted[rank] = my;
    __syncthreads();

    // gather: one wave per row; argmax first-max tie rule; write global
    float* nb_ = nmsG + (size_t)img * (5 * TOPK);
    float* dt_ = detG + (size_t)img * (6 * TOPK);
    for (int r = wv; r < TOPK; r += 16) {
        const u64 key = sorted[r];
        const float conf = __uint_as_float((u32)(key >> 32));
        const bool okrow = conf >= CONF_THRE;
        float x1 = 0.f, y1 = 0.f, x2 = 0.f, y2 = 0.f, clsf = 0.f;
        if (okrow) {
            const u32 anchor = 0xFFFFFFFFu - (u32)(key & 0xFFFFFFFFull);
            const float* row = pred + ((size_t)img * NANCH + anchor) * CH;
            float vv = row[5 + lane];
            int ci = lane;
            if (lane < 16) {
                const float v2 = row[69 + lane];
                if (v2 > vv) { vv = v2; ci = 64 + lane; }
            }
            #pragma unroll
            for (int off = 32; off > 0; off >>= 1) {
                const float ov = __shfl_xor(vv, off);
                const int oi = __shfl_xor(ci, off);
                if (ov > vv || (ov == vv && oi < ci)) { vv = ov; ci = oi; }
            }
            const float cx = row[0], cy = row[1], w = row[2], h = row[3];
            const float hw = w * 0.5f, hh = h * 0.5f;
            x1 = cx - hw; y1 = cy - hh; x2 = cx + hw; y2 = cy + hh;
            clsf = (float)ci;
        }
        if (lane == 0) {
            const float off = clsf * CLS_OFF;
            const float X1 = x1 + off, Y1 = y1 + off, X2 = x2 + off, Y2 = y2 + off;
            nb_[0 * TOPK + r] = X1; nb_[1 * TOPK + r] = Y1;
            nb_[2 * TOPK + r] = X2; nb_[3 * TOPK + r] = Y2;
            nb_[4 * TOPK + r] = (X2 - X1) * (Y2 - Y1);
            dt_[r * 6 + 0] = x1; dt_[r * 6 + 1] = y1;
            dt_[r * 6 + 2] = x2; dt_[r * 6 + 3] = y2;
            dt_[r * 6 + 4] = okrow ? conf : 0.0f;
            dt_[r * 6 + 5] = clsf;
            val[r] = okrow ? 1 : 0;
        }
    }
    __syncthreads();

    if (tid < TOPK) {
        const u64 vb = __ballot(val[tid] != 0);
        if (lane == 0) validG[img * 8 + wv] = vb;
    }
}

// ---- k3 iou: full-chip bitmask, boxes staged in LDS ----
__global__ __launch_bounds__(256) void iou_kernel(const float* __restrict__ nmsG,
                                                  u64* __restrict__ maskG) {
    __shared__ float bx1[TOPK], by1[TOPK], bx2[TOPK], by2[TOPK], bar[TOPK];
    const int img = blockIdx.x;
    const int slab = blockIdx.y;            // 32 slabs x 16 rows
    const int tid = threadIdx.x;
    const int lane = tid & 63;
    const float* nb_ = nmsG + (size_t)img * (5 * TOPK);
    for (int i = tid; i < TOPK; i += 256) {
        bx1[i] = nb_[i];            by1[i] = nb_[TOPK + i];
        bx2[i] = nb_[2 * TOPK + i]; by2[i] = nb_[3 * TOPK + i];
        bar[i] = nb_[4 * TOPK + i];
    }
    __syncthreads();
    const int q0 = slab * (16 * TOPK);
    for (int q = q0 + tid; q < q0 + 16 * TOPK; q += 256) {
        const int i = q >> 9;               // wave-uniform -> LDS broadcast
        const int j = q & (TOPK - 1);       // lane-consecutive -> conflict-free
        bool sup = false;
        if (j > i) {
            const float xx1 = fmaxf(bx1[i], bx1[j]);
            const float yy1 = fmaxf(by1[i], by1[j]);
            const float xx2 = fminf(bx2[i], bx2[j]);
            const float yy2 = fminf(by2[i], by2[j]);
            const float iw = fmaxf(xx2 - xx1, 0.0f);
            const float ih = fmaxf(yy2 - yy1, 0.0f);
            const float inter = iw * ih;
            const float uni = bar[i] + bar[j] - inter;
            const float iou = inter / uni;  // IEEE div, NaN>thre == false (matches ref)
            sup = iou > NMS_THRE;
        }
        const u64 bm = __ballot(sup);
        if (lane == 0) maskG[(size_t)img * 4096 + (q >> 6)] = bm;
    }
}

// ---- k4 greedy: sequential NMS with 4-deep LDS prefetch, branchless update ----
__global__ __launch_bounds__(256) void greedy_kernel(const u64* __restrict__ maskG,
                                                     const u64* __restrict__ validG,
                                                     const float* __restrict__ detG,
                                                     float* __restrict__ out) {
    __shared__ u64 m[TOPK * 8];     // 32 KB
    __shared__ u64 kw8[8];
    const int img = blockIdx.x;
    const int tid = threadIdx.x;
    const int lane = tid & 63;
    const int wv = tid >> 6;
    const u64* mg = maskG + (size_t)img * 4096;
    for (int i = tid; i < 4096; i += 256) m[i] = mg[i];
    __syncthreads();

    if (wv == 0) {
        const bool ld = lane < 8;
        u64 kw = ld ? validG[img * 8 + lane] : 0ull;
        u64 p0 = ld ? m[0 * 8 + lane] : 0ull;
        u64 p1 = ld ? m[1 * 8 + lane] : 0ull;
        u64 p2 = ld ? m[2 * 8 + lane] : 0ull;
        u64 p3 = ld ? m[3 * 8 + lane] : 0ull;
        for (int i = 0; i < TOPK; i += 4) {
            {
                const u64 w = __shfl(kw, i >> 6);
                const u64 bit = (w >> (i & 63)) & 1ull;
                kw &= ~(p0 & (0ull - bit));
                p0 = (ld && i + 4 < TOPK) ? m[(i + 4) * 8 + lane] : 0ull;
            }
            {
                const u64 w = __shfl(kw, (i + 1) >> 6);
                const u64 bit = (w >> ((i + 1) & 63)) & 1ull;
                kw &= ~(p1 & (0ull - bit));
                p1 = (ld && i + 5 < TOPK) ? m[(i + 5) * 8 + lane] : 0ull;
            }
            {
                const u64 w = __shfl(kw, (i + 2) >> 6);
                const u64 bit = (w >> ((i + 2) & 63)) & 1ull;
                kw &= ~(p2 & (0ull - bit));
                p2 = (ld && i + 6 < TOPK) ? m[(i + 6) * 8 + lane] : 0ull;
            }
            {
                const u64 w = __shfl(kw, (i + 3) >> 6);
                const u64 bit = (w >> ((i + 3) & 63)) & 1ull;
                kw &= ~(p3 & (0ull - bit));
                p3 = (ld && i + 7 < TOPK) ? m[(i + 7) * 8 + lane] : 0ull;
            }
        }
        if (ld) kw8[lane] = kw;
    }
    __syncthreads();

    const float* dt_ = detG + (size_t)img * (6 * TOPK);
    float* det_out = out + (size_t)img * (TOPK * 6);
    float* keep_out = out + (size_t)BATCH * TOPK * 6 + (size_t)img * TOPK;
    for (int idx = tid; idx < TOPK * 6; idx += 256) {
        const int r = idx / 6;
        const float kf = ((kw8[r >> 6] >> (r & 63)) & 1ull) ? 1.0f : 0.0f;
        det_out[idx] = dt_[idx] * kf;
    }
    for (int r = tid; r < TOPK; r += 256) {
        keep_out[r] = ((kw8[r >> 6] >> (r & 63)) & 1ull) ? 1.0f : 0.0f;
    }
}

extern "C" void kernel_launch(void* const* d_in, const int* in_sizes, int n_in,
                              void* d_out, int out_size, void* d_ws, size_t ws_size,
                              hipStream_t stream) {
    const float* pred = (const float*)d_in[0];
    float* out = (float*)d_out;
    char* ws = (char*)d_ws;
    u32* conf32 = (u32*)(ws + OFF_CONF);
    float* nmsG = (float*)(ws + OFF_NMS);
    float* detG = (float*)(ws + OFF_DET);
    u64* validG = (u64*)(ws + OFF_VALID);
    u64* maskG = (u64*)(ws + OFF_MASK);

    scan_kernel<<<(BATCH * NANCH) / 16, 256, 0, stream>>>(pred, conf32);
    select_kernel<<<BATCH, 1024, 0, stream>>>(pred, conf32, nmsG, detG, validG);
    dim3 g4(BATCH, 32);
    iou_kernel<<<g4, 256, 0, stream>>>(nmsG, maskG);
    greedy_kernel<<<BATCH, 256, 0, stream>>>(maskG, validG, detG, out);
}

// Round 3
// 449.160 us; speedup vs baseline: 1.1743x; 1.0814x over previous
//
#include <hip/hip_runtime.h>
#include <stdint.h>

#define BATCH 32
#define NANCH 25200
#define CH 85
#define NCLS 80
#define TOPK 512
#define CONF_THRE 0.7f
#define NMS_THRE 0.45f
#define CLS_OFF 4096.0f

typedef unsigned long long u64;
typedef unsigned int u32;

// ws layout (bytes):
//   [0, 3225600)          u32 conf32[32][25200]    (conf bits, 0 if below threshold)
//   [3225600, +327680)    float nms[32][5][512]    x1,y1,x2,y2,area (class-offset)
//   [3553280, +393216)    float det[32][512][6]
//   [3946496, +2048)      u64 valid[32][8]
//   [3948544, +1048576)   u64 mask[32][512][8]
#define OFF_CONF  0
#define OFF_NMS   3225600
#define OFF_DET   3553280
#define OFF_VALID 3946496
#define OFF_MASK  3948544

// ---- k1 scan: wave-transposed, no LDS, no barriers. 16 lanes per anchor. ----
__global__ __launch_bounds__(256) void scan_kernel(const float* __restrict__ pred,
                                                   u32* __restrict__ conf32) {
    const int tid = threadIdx.x;
    const int lane = tid & 63;
    const int wv = tid >> 6;
    const int g = lane >> 4;          // anchor-in-wave 0..3
    const int l = lane & 15;          // lane-in-group
    const int a = blockIdx.x * 16 + wv * 4 + g;     // flat img*NANCH+anchor
    const size_t base = (size_t)a * CH;

    float m = -1.0f, obj = 0.0f;
    {   // p = l*4 .. l*4+3  (covers 0..63)
        const float4 q = *(const float4*)(pred + base + (l << 2));
        const int p = l << 2;
        if (p + 0 >= 5) m = fmaxf(m, q.x); else if (p + 0 == 4) obj = q.x;
        if (p + 1 >= 5) m = fmaxf(m, q.y); else if (p + 1 == 4) obj = q.y;
        if (p + 2 >= 5) m = fmaxf(m, q.z); else if (p + 2 == 4) obj = q.z;
        if (p + 3 >= 5) m = fmaxf(m, q.w); else if (p + 3 == 4) obj = q.w;
    }
    if (l < 5) {                      // p = 64 .. 83 (all classes)
        const float4 q = *(const float4*)(pred + base + 64 + (l << 2));
        m = fmaxf(fmaxf(m, fmaxf(q.x, q.y)), fmaxf(q.z, q.w));
    } else if (l == 5) {              // p = 84
        m = fmaxf(m, pred[base + 84]);
    }
    #pragma unroll
    for (int off = 1; off < 16; off <<= 1) m = fmaxf(m, __shfl_xor(m, off));
    const float ob = __shfl(obj, (lane & 48) + 1);  // lane g*16+1 holds p==4
    const float conf = ob * m;
    if (l == 0)
        conf32[a] = (conf >= CONF_THRE) ? __float_as_uint(conf) : 0u;
}

// ---- k2: fused hist + threshold + single-pass compact + rank sort + gather ----
//      gather: 4 rows per wave (16-lane groups) to cut sequential HBM-latency depth
__global__ __launch_bounds__(1024) void select_kernel(const float* __restrict__ pred,
                                                      const u32* __restrict__ conf32,
                                                      float* __restrict__ nmsG,
                                                      float* __restrict__ detG,
                                                      u64* __restrict__ validG) {
    __shared__ u64 sbuf[1024];
    __shared__ u64 sorted[1024];
    __shared__ u32 hist[256];
    __shared__ u32 wtot[4];
    __shared__ u32 s_cnt, s_pivot;
    __shared__ unsigned char val[TOPK];

    const int img = blockIdx.x;
    const int tid = threadIdx.x;
    const int lane = tid & 63;
    const int wv = tid >> 6;

    if (tid == 0) { s_cnt = 0u; s_pivot = 0u; }   // pivot 0 => T=0x3F000000 selects all valid
    if (tid < 256) hist[tid] = 0u;
    __syncthreads();

    // pass 1: build 256-bin histogram of top-8 mantissa bits (valid bins 102..255)
    const u32* cd = conf32 + (size_t)img * NANCH;
    for (int i = tid; i < NANCH; i += 1024) {
        const u32 c = cd[i];
        if (c) atomicAdd(&hist[(c >> 15) & 255u], 1u);
    }
    __syncthreads();

    // inclusive suffix scan over 256 bins (4 waves + cross-wave totals)
    u32 v = 0, s = 0;
    if (tid < 256) {
        v = hist[tid]; s = v;
        #pragma unroll
        for (int off = 1; off < 64; off <<= 1) {
            const u32 t = __shfl_down(s, off);
            if (lane + off < 64) s += t;
        }
        if (lane == 0) wtot[wv] = s;
    }
    __syncthreads();
    if (tid < 256) {
        u32 add = 0;
        for (int w2 = wv + 1; w2 < 4; ++w2) add += wtot[w2];
        const u32 sfull = s + add;        // count in bins >= tid
        const u32 snext = sfull - v;      // count in bins >  tid
        if (sfull >= TOPK && snext < TOPK) s_pivot = (u32)tid;
    }
    __syncthreads();
    const u32 T = 0x3F000000u | (s_pivot << 15);

    // pass 2 (L2-hot): compact conf >= T (order-free; rank sort restores exact order)
    for (int i = tid; i < NANCH; i += 1024) {
        const u32 c = cd[i];
        if (c >= T) {
            const u32 pos = atomicAdd(&s_cnt, 1u);
            if (pos < 1024u)
                sbuf[pos] = ((u64)c << 32) | (u64)(0xFFFFFFFFu - (u32)i);
        }
    }
    __syncthreads();
    const u32 mc = (s_cnt > 1024u) ? 1024u : s_cnt;

    // rank sort (keys unique by anchor): rank = #{key' > key}
    sorted[tid] = 0ull;
    u32 rank = 0; u64 my = 0ull;
    if (tid < (int)mc) {
        my = sbuf[tid];
        for (u32 i = 0; i < mc; ++i) rank += (sbuf[i] > my) ? 1u : 0u;
    }
    __syncthreads();
    if (tid < (int)mc && rank < 1024u) sorted[rank] = my;
    __syncthreads();

    // gather: 4 rows per wave via 16-lane groups; 8 sequential batches of 64 rows.
    // lane l covers classes {l, 16+l, 32+l, 48+l, 64+l}; argmax first-max tie rule.
    const int g = lane >> 4;          // row-in-wave 0..3
    const int l = lane & 15;          // lane-in-group
    float* nb_ = nmsG + (size_t)img * (5 * TOPK);
    float* dt_ = detG + (size_t)img * (6 * TOPK);
    for (int pass = 0; pass < 8; ++pass) {
        const int r = pass * 64 + wv * 4 + g;
        const u64 key = sorted[r];
        const float conf = __uint_as_float((u32)(key >> 32));
        const bool okrow = conf >= CONF_THRE;
        float x1 = 0.f, y1 = 0.f, x2 = 0.f, y2 = 0.f, clsf = 0.f;
        float vv = -1.0f;
        int ci = l;
        if (okrow) {
            const u32 anchor = 0xFFFFFFFFu - (u32)(key & 0xFFFFFFFFull);
            const float* row = pred + ((size_t)img * NANCH + anchor) * CH;
            // 5 independent strided loads + box load, all issued together
            const float v0 = row[5 + l];
            const float v1 = row[21 + l];
            const float v2 = row[37 + l];
            const float v3 = row[53 + l];
            const float v4 = row[69 + l];
            float4 box;
            if (l == 0) box = *(const float4*)row;
            vv = v0; ci = l;
            if (v1 > vv) { vv = v1; ci = 16 + l; }
            if (v2 > vv) { vv = v2; ci = 32 + l; }
            if (v3 > vv) { vv = v3; ci = 48 + l; }
            if (v4 > vv) { vv = v4; ci = 64 + l; }
            // reduce within 16-lane group: larger value wins; tie -> lower class idx
            #pragma unroll
            for (int off = 8; off > 0; off >>= 1) {
                const float ov = __shfl_xor(vv, off);
                const int oi = __shfl_xor(ci, off);
                if (ov > vv || (ov == vv && oi < ci)) { vv = ov; ci = oi; }
            }
            if (l == 0) {
                const float hw = box.z * 0.5f, hh = box.w * 0.5f;
                x1 = box.x - hw; y1 = box.y - hh; x2 = box.x + hw; y2 = box.y + hh;
                clsf = (float)ci;
            }
        }
        if (l == 0) {
            const float off = clsf * CLS_OFF;
            const float X1 = x1 + off, Y1 = y1 + off, X2 = x2 + off, Y2 = y2 + off;
            nb_[0 * TOPK + r] = X1; nb_[1 * TOPK + r] = Y1;
            nb_[2 * TOPK + r] = X2; nb_[3 * TOPK + r] = Y2;
            nb_[4 * TOPK + r] = (X2 - X1) * (Y2 - Y1);
            dt_[r * 6 + 0] = x1; dt_[r * 6 + 1] = y1;
            dt_[r * 6 + 2] = x2; dt_[r * 6 + 3] = y2;
            dt_[r * 6 + 4] = okrow ? conf : 0.0f;
            dt_[r * 6 + 5] = clsf;
            val[r] = okrow ? 1 : 0;
        }
    }
    __syncthreads();

    if (tid < TOPK) {
        const u64 vb = __ballot(val[tid] != 0);
        if (lane == 0) validG[img * 8 + wv] = vb;
    }
}

// ---- k3 iou: full-chip bitmask, boxes staged in LDS ----
__global__ __launch_bounds__(256) void iou_kernel(const float* __restrict__ nmsG,
                                                  u64* __restrict__ maskG) {
    __shared__ float bx1[TOPK], by1[TOPK], bx2[TOPK], by2[TOPK], bar[TOPK];
    const int img = blockIdx.x;
    const int slab = blockIdx.y;            // 32 slabs x 16 rows
    const int tid = threadIdx.x;
    const int lane = tid & 63;
    const float* nb_ = nmsG + (size_t)img * (5 * TOPK);
    for (int i = tid; i < TOPK; i += 256) {
        bx1[i] = nb_[i];            by1[i] = nb_[TOPK + i];
        bx2[i] = nb_[2 * TOPK + i]; by2[i] = nb_[3 * TOPK + i];
        bar[i] = nb_[4 * TOPK + i];
    }
    __syncthreads();
    const int q0 = slab * (16 * TOPK);
    for (int q = q0 + tid; q < q0 + 16 * TOPK; q += 256) {
        const int i = q >> 9;               // wave-uniform -> LDS broadcast
        const int j = q & (TOPK - 1);       // lane-consecutive -> conflict-free
        bool sup = false;
        if (j > i) {
            const float xx1 = fmaxf(bx1[i], bx1[j]);
            const float yy1 = fmaxf(by1[i], by1[j]);
            const float xx2 = fminf(bx2[i], bx2[j]);
            const float yy2 = fminf(by2[i], by2[j]);
            const float iw = fmaxf(xx2 - xx1, 0.0f);
            const float ih = fmaxf(yy2 - yy1, 0.0f);
            const float inter = iw * ih;
            const float uni = bar[i] + bar[j] - inter;
            const float iou = inter / uni;  // IEEE div, NaN>thre == false (matches ref)
            sup = iou > NMS_THRE;
        }
        const u64 bm = __ballot(sup);
        if (lane == 0) maskG[(size_t)img * 4096 + (q >> 6)] = bm;
    }
}

// ---- k4 greedy: sequential NMS with 4-deep LDS prefetch, branchless update ----
__global__ __launch_bounds__(256) void greedy_kernel(const u64* __restrict__ maskG,
                                                     const u64* __restrict__ validG,
                                                     const float* __restrict__ detG,
                                                     float* __restrict__ out) {
    __shared__ u64 m[TOPK * 8];     // 32 KB
    __shared__ u64 kw8[8];
    const int img = blockIdx.x;
    const int tid = threadIdx.x;
    const int lane = tid & 63;
    const int wv = tid >> 6;
    const u64* mg = maskG + (size_t)img * 4096;
    for (int i = tid; i < 4096; i += 256) m[i] = mg[i];
    __syncthreads();

    if (wv == 0) {
        const bool ld = lane < 8;
        u64 kw = ld ? validG[img * 8 + lane] : 0ull;
        u64 p0 = ld ? m[0 * 8 + lane] : 0ull;
        u64 p1 = ld ? m[1 * 8 + lane] : 0ull;
        u64 p2 = ld ? m[2 * 8 + lane] : 0ull;
        u64 p3 = ld ? m[3 * 8 + lane] : 0ull;
        for (int i = 0; i < TOPK; i += 4) {
            {
                const u64 w = __shfl(kw, i >> 6);
                const u64 bit = (w >> (i & 63)) & 1ull;
                kw &= ~(p0 & (0ull - bit));
                p0 = (ld && i + 4 < TOPK) ? m[(i + 4) * 8 + lane] : 0ull;
            }
            {
                const u64 w = __shfl(kw, (i + 1) >> 6);
                const u64 bit = (w >> ((i + 1) & 63)) & 1ull;
                kw &= ~(p1 & (0ull - bit));
                p1 = (ld && i + 5 < TOPK) ? m[(i + 5) * 8 + lane] : 0ull;
            }
            {
                const u64 w = __shfl(kw, (i + 2) >> 6);
                const u64 bit = (w >> ((i + 2) & 63)) & 1ull;
                kw &= ~(p2 & (0ull - bit));
                p2 = (ld && i + 6 < TOPK) ? m[(i + 6) * 8 + lane] : 0ull;
            }
            {
                const u64 w = __shfl(kw, (i + 3) >> 6);
                const u64 bit = (w >> ((i + 3) & 63)) & 1ull;
                kw &= ~(p3 & (0ull - bit));
                p3 = (ld && i + 7 < TOPK) ? m[(i + 7) * 8 + lane] : 0ull;
            }
        }
        if (ld) kw8[lane] = kw;
    }
    __syncthreads();

    const float* dt_ = detG + (size_t)img * (6 * TOPK);
    float* det_out = out + (size_t)img * (TOPK * 6);
    float* keep_out = out + (size_t)BATCH * TOPK * 6 + (size_t)img * TOPK;
    for (int idx = tid; idx < TOPK * 6; idx += 256) {
        const int r = idx / 6;
        const float kf = ((kw8[r >> 6] >> (r & 63)) & 1ull) ? 1.0f : 0.0f;
        det_out[idx] = dt_[idx] * kf;
    }
    for (int r = tid; r < TOPK; r += 256) {
        keep_out[r] = ((kw8[r >> 6] >> (r & 63)) & 1ull) ? 1.0f : 0.0f;
    }
}

extern "C" void kernel_launch(void* const* d_in, const int* in_sizes, int n_in,
                              void* d_out, int out_size, void* d_ws, size_t ws_size,
                              hipStream_t stream) {
    const float* pred = (const float*)d_in[0];
    float* out = (float*)d_out;
    char* ws = (char*)d_ws;
    u32* conf32 = (u32*)(ws + OFF_CONF);
    float* nmsG = (float*)(ws + OFF_NMS);
    float* detG = (float*)(ws + OFF_DET);
    u64* validG = (u64*)(ws + OFF_VALID);
    u64* maskG = (u64*)(ws + OFF_MASK);

    scan_kernel<<<(BATCH * NANCH) / 16, 256, 0, stream>>>(pred, conf32);
    select_kernel<<<BATCH, 1024, 0, stream>>>(pred, conf32, nmsG, detG, validG);
    dim3 g4(BATCH, 32);
    iou_kernel<<<g4, 256, 0, stream>>>(nmsG, maskG);
    greedy_kernel<<<BATCH, 256, 0, stream>>>(maskG, validG, detG, out);
}